// Round 14
// baseline (118.334 us; speedup 1.0000x reference)
//
#include <hip/hip_runtime.h>

// SDFLoss: P=64 people, V=6890 verts, 32^3 SDF-band proxy grid, trilinear
// cross-sampling, scalar loss.
//
// 2 kernels (launch gaps ~8-10us each in this harness, so fewer = faster):
//   k_phi    : per-block-local bbox scan (redundant x4, no inter-block dep),
//              fp8 pair volume (z-slab + wave y-row culls), zeroes accumulators
//   k_sample : per-wave redundant validity ballot (mask stays in SGPR),
//              LDS-staged pair volume, mask-walk j-loop with zero loads in
//              the loop-carried chain (raw AoS verts, dwordx3), last-block
//              finalize.
//
// phi: fully zero-padded PAIR volume, u16 at (iz,iy,ix), idx 0..33 = grid
// -1..32, holding (phi[gx], phi[gx+1]) as 2x fp8(e4m3) scaled x64.
// 34^3 x 2B = 78,608 B -> 2 blocks/CU in k_sample.

#define NP 64
#define NVERT 6890
#define NV3 (NVERT*3)
#define GRD 32
#define QDIM 34                   // -1..32 per axis
#define QPLANE (QDIM*QDIM)        // 1156 entries
#define QVOL (QDIM*QPLANE)        // 39304 entries = 78608 B
#define VSUB 256
#define VSTRIDE 26                // NVERT / VSUB
#define BAND 0.15f
#define PHI_SCALE 64.0f
#define INV_PHI_SCALE 0.015625f
#define LDS_BYTES (QVOL*2 + 64)
#define SAMPLE_BLOCKS (8*NP)

typedef float floatx2 __attribute__((ext_vector_type(2)));

__device__ __forceinline__ float wave_min(float v) {
  #pragma unroll
  for (int off = 32; off > 0; off >>= 1) v = fminf(v, __shfl_down(v, off));
  return v;
}
__device__ __forceinline__ float wave_max(float v) {
  #pragma unroll
  for (int off = 32; off > 0; off >>= 1) v = fmaxf(v, __shfl_down(v, off));
  return v;
}
__device__ __forceinline__ float wave_sum(float v) {
  #pragma unroll
  for (int off = 32; off > 0; off >>= 1) v += __shfl_down(v, off);
  return v;
}

// -------- kernel 1: phi pair volume; block-local bbox; zero accs --------
// grid = NP*4 blocks of 1024 threads: block (p, zq) does z-planes zq*8..zq*8+7.
__global__ __launch_bounds__(1024) void k_phi(
    const float* __restrict__ verts, const float* __restrict__ trans,
    unsigned short* __restrict__ pairs, float* __restrict__ bbox,
    float* __restrict__ accp, unsigned int* __restrict__ donep) {
  int p = blockIdx.x >> 2;
  int zq = blockIdx.x & 3;
  int tid = threadIdx.x;
  int x = tid & 31, y = tid >> 5;

  __shared__ float kv[VSUB][3];       // z-culled vertex list
  __shared__ float phib[8][32][32];   // 32 KB
  __shared__ float s[16][6];
  __shared__ float bbf[6];
  __shared__ int nkeep;

  if (blockIdx.x == 0 && tid == 0) { accp[0] = 0.0f; donep[0] = 0u; }

  // ---- block-local bbox of person p (redundant across the 4 zq blocks) ----
  const float* vp = verts + (size_t)p * NV3;
  float tx = trans[p*3+0], ty = trans[p*3+1], tz = trans[p*3+2];
  float mnx=1e30f, mny=1e30f, mnz=1e30f, mxx=-1e30f, mxy=-1e30f, mxz=-1e30f;
  for (int v = tid; v < NVERT; v += 1024) {
    float xx = vp[v*3+0]+tx, yy = vp[v*3+1]+ty, zz = vp[v*3+2]+tz;
    mnx=fminf(mnx,xx); mny=fminf(mny,yy); mnz=fminf(mnz,zz);
    mxx=fmaxf(mxx,xx); mxy=fmaxf(mxy,yy); mxz=fmaxf(mxz,zz);
  }
  mnx=wave_min(mnx); mny=wave_min(mny); mnz=wave_min(mnz);
  mxx=wave_max(mxx); mxy=wave_max(mxy); mxz=wave_max(mxz);
  int wave = tid >> 6, lane = tid & 63;
  if (lane == 0) {
    s[wave][0]=mnx; s[wave][1]=mny; s[wave][2]=mnz;
    s[wave][3]=mxx; s[wave][4]=mxy; s[wave][5]=mxz;
  }
  __syncthreads();
  if (tid == 0) {
    float a0=s[0][0],a1=s[0][1],a2=s[0][2],b0=s[0][3],b1=s[0][4],b2=s[0][5];
    for (int w = 1; w < 16; ++w) {
      a0=fminf(a0,s[w][0]); a1=fminf(a1,s[w][1]); a2=fminf(a2,s[w][2]);
      b0=fmaxf(b0,s[w][3]); b1=fmaxf(b1,s[w][4]); b2=fmaxf(b2,s[w][5]);
    }
    bbf[0]=a0; bbf[1]=a1; bbf[2]=a2; bbf[3]=b0; bbf[4]=b1; bbf[5]=b2;
    bbox[p*3+0]=a0; bbox[p*3+1]=a1; bbox[p*3+2]=a2;              // bmin
    bbox[192+p*3+0]=b0; bbox[192+p*3+1]=b1; bbox[192+p*3+2]=b2;  // bmax
    nkeep = 0;
  }
  __syncthreads();

  float cx = 0.5f*(bbf[0]+bbf[3]), cy = 0.5f*(bbf[1]+bbf[4]);
  float cz = 0.5f*(bbf[2]+bbf[5]);
  float ext = fmaxf(bbf[3]-bbf[0], fmaxf(bbf[4]-bbf[1], bbf[5]-bbf[2]));
  float is = 1.0f / (0.6f * ext);      // (1+0.2)*0.5 * ext
  const float inv = 1.0f / (float)GRD;

  // z-slab cull: vert can only matter if z-distance to slab range < BAND
  if (tid < VSUB) {
    int v = tid * VSTRIDE;
    const float* vv = vp + (size_t)v * 3;
    float X = (vv[0] + tx - cx) * is;
    float Y = (vv[1] + ty - cy) * is;
    float Z = (vv[2] + tz - cz) * is;
    float zlo = (2.0f*(zq*8)     + 1.0f) * inv - 1.0f;
    float zhi = (2.0f*(zq*8 + 7) + 1.0f) * inv - 1.0f;
    float dz = fmaxf(fmaxf(zlo - Z, Z - zhi), 0.0f);
    if (dz < BAND) {
      int idx = atomicAdd(&nkeep, 1);
      kv[idx][0] = X; kv[idx][1] = Y; kv[idx][2] = Z;
    }
  }
  __syncthreads();
  int nk = nkeep;

  float gx = (2.0f*x + 1.0f) * inv - 1.0f;
  float gy = (2.0f*y + 1.0f) * inv - 1.0f;
  float gz[8];
  #pragma unroll
  for (int k = 0; k < 8; ++k) gz[k] = (2.0f*(zq*8+k) + 1.0f) * inv - 1.0f;

  float d2[8];
  #pragma unroll
  for (int k = 0; k < 8; ++k) d2[k] = 1e30f;

  // per-wave y-row cull: wave w owns rows y = {2w, 2w+1}
  int w = tid >> 6;
  float ylo = (4.0f*w + 1.0f) * inv - 1.0f;
  float yhi = (4.0f*w + 3.0f) * inv - 1.0f;

  for (int v = 0; v < nk; ++v) {
    float Y = kv[v][1];                              // broadcast read
    if (fmaxf(ylo - Y, Y - yhi) >= BAND) continue;   // wave-uniform skip
    float dx = gx - kv[v][0];
    float dy = gy - Y;
    float vz = kv[v][2];
    float r2 = fmaf(dy, dy, dx*dx);
    #pragma unroll
    for (int k = 0; k < 8; ++k) {
      float dz = gz[k] - vz;
      d2[k] = fminf(d2[k], fmaf(dz, dz, r2));
    }
  }
  #pragma unroll
  for (int k = 0; k < 8; ++k)
    phib[k][y][x] = fmaxf(BAND - sqrtf(d2[k]), 0.0f) * PHI_SCALE;
  __syncthreads();

  // pair assembly: u16 at (iz, iy, ix); gy = iy-1, gx = ix-1
  unsigned short* qp = pairs + (size_t)p * QVOL;
  for (int idx = tid; idx < QPLANE; idx += 1024) {
    int iy = idx / QDIM, ix = idx % QDIM;
    int gyy = iy - 1, gxx = ix - 1;
    bool gyok = (unsigned)gyy < 32u;
    bool aok = gyok && ((unsigned)gxx < 32u);
    bool bok = gyok && ((unsigned)ix  < 32u);
    int ya = gyok ? gyy : 0;
    int xa = aok ? gxx : 0;
    int xb = bok ? ix : 0;
    #pragma unroll
    for (int k = 0; k < 8; ++k) {
      float a = aok ? phib[k][ya][xa] : 0.0f;
      float b = bok ? phib[k][ya][xb] : 0.0f;
      int pk = __builtin_amdgcn_cvt_pk_fp8_f32(a, b, 0, false);
      qp[(zq*8 + k + 1)*QPLANE + idx] = (unsigned short)(pk & 0xffff);
    }
    if (zq == 0) qp[idx] = 0;                  // plane 0  (gz = -1)
    if (zq == 3) qp[33*QPLANE + idx] = 0;      // plane 33 (gz = 32)
  }
}

// -------- trilinear sample from the LDS pair volume --------
__device__ __forceinline__ float qsample(const unsigned short* q,
                                         float X, float Y, float Z) {
  X = fminf(fmaxf(X, 0.0f), 33.99f);
  Y = fminf(fmaxf(Y, 0.0f), 32.999f);
  Z = fminf(fmaxf(Z, 0.0f), 32.999f);
  float xf = floorf(X), yf = floorf(Y), zf = floorf(Z);
  float fx = X - xf, fy = Y - yf, fz = Z - zf;
  int e = ((int)zf * QDIM + (int)yf) * QDIM + (int)xf;
  unsigned int w00 = q[e];
  unsigned int w10 = q[e + QDIM];
  unsigned int w01 = q[e + QPLANE];
  unsigned int w11 = q[e + QPLANE + QDIM];
  floatx2 c00 = __builtin_amdgcn_cvt_pk_f32_fp8((int)w00, false);
  floatx2 c10 = __builtin_amdgcn_cvt_pk_f32_fp8((int)w10, false);
  floatx2 c01 = __builtin_amdgcn_cvt_pk_f32_fp8((int)w01, false);
  floatx2 c11 = __builtin_amdgcn_cvt_pk_f32_fp8((int)w11, false);
  float u00 = fmaf(fx, c00.y - c00.x, c00.x);
  float u10 = fmaf(fx, c10.y - c10.x, c10.x);
  float u01 = fmaf(fx, c01.y - c01.x, c01.x);
  float u11 = fmaf(fx, c11.y - c11.x, c11.x);
  float a0 = fmaf(fy, u10 - u00, u00);
  float a1 = fmaf(fy, u11 - u01, u01);
  return fmaf(fz, a1 - a0, a0);
}

// -------- kernel 2: ballot + sample + reduce + last-block finalize --------
__global__ __launch_bounds__(896, 7) void k_sample(
    const float* __restrict__ verts, const float* __restrict__ trans,
    const float* __restrict__ bbox, const unsigned short* __restrict__ pairs,
    float* __restrict__ accp, unsigned int* __restrict__ donep,
    float* __restrict__ out) {
  extern __shared__ unsigned char smem[];
  const unsigned short* sq = (const unsigned short*)smem;
  float* red = (float*)(smem + (size_t)QVOL * 2);

  int i = blockIdx.y;
  int tid = threadIdx.x;
  int lane = tid & 63;

  // per-wave redundant validity ballot: lane l = person l; mask stays SGPR
  float amn0 = bbox[lane*3+0], amn1 = bbox[lane*3+1], amn2 = bbox[lane*3+2];
  float amx0 = bbox[192+lane*3+0], amx1 = bbox[192+lane*3+1],
        amx2 = bbox[192+lane*3+2];
  bool valid = true;
  for (int j = 0; j < NP; ++j) {
    valid = valid && (amn0 <= bbox[192+j*3+0]) && (bbox[j*3+0] <= amx0)
                  && (amn1 <= bbox[192+j*3+1]) && (bbox[j*3+1] <= amx1)
                  && (amn2 <= bbox[192+j*3+2]) && (bbox[j*3+2] <= amx2);
  }
  unsigned long long mask = __ballot(valid);
  int nvi = (int)__popcll(mask);
  bool active = (mask >> i) & 1ull;

  // center/scale of person i (uniform scalar loads)
  float bx0 = bbox[i*3+0], by0 = bbox[i*3+1], bz0 = bbox[i*3+2];
  float bx1 = bbox[192+i*3+0], by1 = bbox[192+i*3+1], bz1 = bbox[192+i*3+2];
  float ext = fmaxf(bx1-bx0, fmaxf(by1-by0, bz1-bz0));
  float s16 = 16.0f / (0.6f * ext);
  float cx = 0.5f*(bx0+bx1), cy = 0.5f*(by0+by1), cz = 0.5f*(bz0+bz1);

  if (active && nvi > 1) {
    // stage pair volume (78608 B = 4913 uint4) into LDS
    {
      const uint4* src = (const uint4*)(pairs + (size_t)i * QVOL);
      uint4* dst = (uint4*)smem;
      for (int t = tid; t < QVOL/8; t += 896) dst[t] = src[t];
    }
    __syncthreads();

    int v = blockIdx.x * 896 + tid;
    bool ok = v < NVERT;
    int vc = ok ? v : 0;
    // +1 volume-index offset folded: 15.5 + 1 = 16.5
    float bx = fmaf(-cx, s16, 16.5f) + (ok ? 0.0f : 1e9f);
    float by = fmaf(-cy, s16, 16.5f);
    float bz = fmaf(-cz, s16, 16.5f);

    float acc = 0.0f;
    #pragma unroll 2
    for (int jj = 0; jj < NP; ++jj) {
      if (jj == i || !((mask >> jj) & 1ull)) continue;   // SALU-only test
      const float* vj = verts + ((size_t)jj * NVERT + vc) * 3;
      float vx = vj[0], vy = vj[1], vz = vj[2];          // one dwordx3
      float oxj = fmaf(trans[jj*3+0], s16, bx);          // scalar trans fold
      float oyj = fmaf(trans[jj*3+1], s16, by);
      float ozj = fmaf(trans[jj*3+2], s16, bz);
      acc += qsample(sq, fmaf(vx, s16, oxj), fmaf(vy, s16, oyj),
                     fmaf(vz, s16, ozj));
    }

    acc = wave_sum(acc);
    int wv = tid >> 6;
    if (lane == 0) red[wv] = acc;
    __syncthreads();
    if (tid == 0) {
      float tot = 0.0f;
      #pragma unroll
      for (int w = 0; w < 14; ++w) tot += red[w];
      atomicAdd(accp, tot * INV_PHI_SCALE);
    }
  }

  // last-block finalize; every block increments
  if (tid == 0) {
    __threadfence();
    unsigned int old = atomicAdd(donep, 1u);
    if (old == SAMPLE_BLOCKS - 1) {
      float nv = fmaxf((float)nvi, 1.0f);
      float loss = atomicAdd(accp, 0.0f);      // coherent read
      out[0] = loss / (nv * nv);
    }
  }
}

extern "C" void kernel_launch(void* const* d_in, const int* in_sizes, int n_in,
                              void* d_out, int out_size, void* d_ws, size_t ws_size,
                              hipStream_t stream) {
  const float* verts = (const float*)d_in[0];   // [64,6890,3]
  const float* trans = (const float*)d_in[1];   // [64,3]
  float* out = (float*)d_out;

  unsigned short* pairs = (unsigned short*)d_ws;      // 64*39304*2 B = 5.03 MB
  float* bbox      = (float*)((unsigned char*)d_ws + (size_t)NP * QVOL * 2);
  float* accp      = bbox + 384;                      // loss accumulator
  unsigned int* donep = (unsigned int*)(accp + 1);    // done-block counter

  hipFuncSetAttribute((const void*)k_sample,
                      hipFuncAttributeMaxDynamicSharedMemorySize, LDS_BYTES);

  k_phi<<<NP*4, 1024, 0, stream>>>(verts, trans, pairs, bbox, accp, donep);
  k_sample<<<dim3(8, NP), 896, LDS_BYTES, stream>>>(verts, trans, bbox, pairs,
                                                    accp, donep, out);
}